// Round 11
// baseline (65.760 us; speedup 1.0000x reference)
//
#include <hip/hip_runtime.h>
#include <hip/hip_bf16.h>

namespace {
constexpr int NB    = 64;
constexpr int V0d   = 40, V1d = 40, V2d = 200;
constexpr int VOL   = V0d * V1d * V2d;        // 320,000
constexpr int NC0   = 5, NC1 = 5, NC2 = 21;
constexpr int CELLS = NC0 * NC1 * NC2;        // 525
constexpr int M     = NB * CELLS;             // 33600
constexpr int C1MAX = 104, C2MAX = 120;
constexpr int KS    = 104 * C1MAX * C2MAX;    // 1,297,920 dense compact keys
constexpr int NWORDS = KS / 32;               // 40,560 bitmask words
constexpr int NSB    = (NWORDS + 255) / 256;  // 159 scan blocks
constexpr int NWPAD  = NSB * 256;             // 40,704
constexpr int CHVOL  = 1000;
constexpr int RPB    = 8;                     // ranks per k_out block (serial)
constexpr int NQ     = M / RPB;               // 4200 = 8 * 525
}

typedef float f32x4 __attribute__((ext_vector_type(4)));

// Round through bf16 (expected outputs are bf16-rounded float32 values).
__device__ __forceinline__ float bf16r(float v) {
    return __bfloat162float(__float2bfloat16(v));
}

__device__ __forceinline__ int enc(int c0, int c1, int c2) {
    return (c0 * C1MAX + c1) * C2MAX + c2;
}

// zero key-bitmask W only (162 KB)
__global__ void k_zero(int4* __restrict__ W4) {
    int idx = blockIdx.x * blockDim.x + threadIdx.x;
    int stride = gridDim.x * blockDim.x;
    const int w4 = NWORDS / 4;          // 10,140
    for (int i = idx; i < w4; i += stride) W4[i] = make_int4(0, 0, 0, 0);
}

// mark keys; also zero the contributor masks (disjoint array, no hazard)
__global__ void k_mark(const int* __restrict__ loc, unsigned* __restrict__ W,
                       int4* __restrict__ mask4) {
    int m = blockIdx.x * blockDim.x + threadIdx.x;
    if (m < M * 8 / 16) mask4[m] = make_int4(0, 0, 0, 0);   // 16,800 int4
    if (m >= M) return;
    int b = m / CELLS, cell = m % CELLS;
    int i = cell / (NC1 * NC2), j = (cell / NC2) % NC1, k = cell % NC2;
    int d = enc(loc[b * 3 + 0] / 10 + i, loc[b * 3 + 1] / 10 + j,
                loc[b * 3 + 2] / 10 + k);
    atomicOr(&W[d >> 5], 1u << (d & 31));
}

// per-word exclusive popcount prefix within each 256-word block
__global__ __launch_bounds__(256) void k_scan_words(const unsigned* __restrict__ W,
                                                    unsigned* __restrict__ WP,
                                                    int* __restrict__ Bsums) {
    int t = threadIdx.x;
    int w = blockIdx.x * 256 + t;
    int c = (w < NWORDS) ? __popc(W[w]) : 0;
    __shared__ int sc[256];
    sc[t] = c;
    __syncthreads();
#pragma unroll
    for (int off = 1; off < 256; off <<= 1) {
        int x = (t >= off) ? sc[t - off] : 0;
        __syncthreads();
        sc[t] += x;
        __syncthreads();
    }
    int incl = sc[t];
    WP[w] = (unsigned)(incl - c);
    if (t == 255) Bsums[blockIdx.x] = incl;
}

// rank every tile; block-local redundant scan of the 159 Bsums replaces the
// separate k_scan_sums launch. Record unique key + contributor bitmask.
__global__ __launch_bounds__(256) void k_slots(const int* __restrict__ loc,
        const unsigned* __restrict__ W, const unsigned* __restrict__ WP,
        const int* __restrict__ Bsums, int* __restrict__ ukeys,
        unsigned long long* __restrict__ mask) {
    int t = threadIdx.x;
    __shared__ int sBase[256];
    int bv = (t < NSB) ? Bsums[t] : 0;
    __shared__ int sc[256];
    sc[t] = bv;
    __syncthreads();
#pragma unroll
    for (int off = 1; off < 256; off <<= 1) {
        int x = (t >= off) ? sc[t - off] : 0;
        __syncthreads();
        sc[t] += x;
        __syncthreads();
    }
    sBase[t] = sc[t] - bv;               // exclusive prefix of block sums
    __syncthreads();

    int m = blockIdx.x * blockDim.x + t;
    if (m >= M) return;
    int b = m / CELLS, cell = m % CELLS;
    int i = cell / (NC1 * NC2), j = (cell / NC2) % NC1, k = cell % NC2;
    int d = enc(loc[b * 3 + 0] / 10 + i, loc[b * 3 + 1] / 10 + j,
                loc[b * 3 + 2] / 10 + k);
    int w = d >> 5, bp = d & 31;
    int rank = sBase[w >> 8] + (int)WP[w] + __popc(W[w] & ((1u << bp) - 1u));
    ukeys[rank] = d;                     // same value from all writers
    atomicOr(&mask[rank], 1ull << b);    // order-independent -> deterministic
}

// 8 sequential ranks per block (persistent-ish): 8x fewer block setups,
// 1-deep scalar prefetch of next rank's mask/key; gather body = proven
// dual-path + non-temporal stores. All state named scalars.
__global__ __launch_bounds__(256) void k_out(const float* __restrict__ data,
        const int* __restrict__ loc, const int* __restrict__ ukeys,
        const unsigned long long* __restrict__ mask,
        float* __restrict__ out, long long base_ul) {
    // bijective XCD swizzle on rank-octets: NQ = 4200 = 8 * 525
    int orig = blockIdx.x;
    int q = (orig & 7) * (NQ / 8) + (orig >> 3);
    int r0 = q * RPB;
    int t = threadIdx.x;
    bool act = (t < 250);

    // element decode once (elems e0..e0+3 of the 1000-float chunk)
    int e0 = t * 4;
    int x  = e0 / 100;
    int rm = e0 % 100;
    int y  = rm / 10;
    int z0 = rm % 10;                    // in {0,2,4,6,8}

    unsigned long long mk_n = mask[r0];  // prefetched scalar state
    int key_n = ukeys[r0];

    for (int rk = 0; rk < RPB; ++rk) {
        int r = r0 + rk;
        unsigned long long mk = mk_n;
        int key = key_n;
        if (rk < RPB - 1) {              // prefetch next rank's uniforms
            mk_n  = mask[r + 1];
            key_n = ukeys[r + 1];
        }
        float ax = 0.f, ay = 0.f, az = 0.f, aw = 0.f;
        if (mk != 0ull && act) {
            int c0 = key / (C1MAX * C2MAX);
            int rem = key % (C1MAX * C2MAX);
            int g0 = c0 * 10, g1 = (rem / C2MAX) * 10, g2 = (rem % C2MAX) * 10;
            unsigned long long m2 = mk;
            while (m2) {                 // ascending b == numpy order
                int b = __builtin_ctzll(m2);
                m2 &= m2 - 1;
                int l0 = loc[b * 3 + 0], l1 = loc[b * 3 + 1], l2 = loc[b * 3 + 2];
                const float* db = data + (size_t)b * VOL;
                if (z0 <= 6) {
                    // all 4 elems share one source row (x,y)
                    int p0 = g0 - l0 + x, p1 = g1 - l1 + y, p2 = g2 - l2 + z0;
                    if ((unsigned)p0 < (unsigned)V0d &&
                        (unsigned)p1 < (unsigned)V1d) {
                        const float* s = db + (p0 * V1d + p1) * V2d + p2;
                        if (p2 >= 0 && p2 <= V2d - 4) {
                            ax += s[0]; ay += s[1]; az += s[2]; aw += s[3];
                        } else {
                            if ((unsigned)p2       < (unsigned)V2d) ax += s[0];
                            if ((unsigned)(p2 + 1) < (unsigned)V2d) ay += s[1];
                            if ((unsigned)(p2 + 2) < (unsigned)V2d) az += s[2];
                            if ((unsigned)(p2 + 3) < (unsigned)V2d) aw += s[3];
                        }
                    }
                } else {
                    // z0 == 8: group straddles a y-row boundary; per-element
                    float av0 = 0.f, av1 = 0.f, av2 = 0.f, av3 = 0.f;
#pragma unroll
                    for (int jj = 0; jj < 4; ++jj) {
                        int e  = e0 + jj;
                        int xx = e / 100;
                        int rj = e % 100;
                        int yy = rj / 10, zz = rj % 10;
                        int q0 = g0 - l0 + xx, q1 = g1 - l1 + yy,
                            q2 = g2 - l2 + zz;
                        if ((unsigned)q0 < (unsigned)V0d &&
                            (unsigned)q1 < (unsigned)V1d &&
                            (unsigned)q2 < (unsigned)V2d) {
                            float v = db[(q0 * V1d + q1) * V2d + q2];
                            if (jj == 0) av0 = v; else if (jj == 1) av1 = v;
                            else if (jj == 2) av2 = v; else av3 = v;
                        }
                    }
                    ax += av0; ay += av1; az += av2; aw += av3;
                }
            }
        }
        if (act) {
            f32x4 v = {bf16r(ax), bf16r(ay), bf16r(az), bf16r(aw)};
            __builtin_nontemporal_store(v,
                reinterpret_cast<f32x4*>(out + (long long)r * CHVOL + e0));
        }
    }

    // fused uloc writes (output 1): lane t<8 handles rank r0+t
    if (t < RPB) {
        int r = r0 + t;
        unsigned long long mkv = mask[r];
        float u0, u1, u2;
        if (mkv != 0ull) {
            int key = ukeys[r];
            int rem = key % (C1MAX * C2MAX);
            u0 = (float)((key / (C1MAX * C2MAX)) * 10);
            u1 = (float)((rem / C2MAX) * 10);
            u2 = (float)((rem % C2MAX) * 10);
        } else {  // jnp.unique fill 2^31-1 decoded: (327670, 2550, 2550)
            u0 = 327670.f; u1 = 2550.f; u2 = 2550.f;
        }
        long long i = base_ul + (long long)r * 3;
        __builtin_nontemporal_store(bf16r(u0), out + i + 0);
        __builtin_nontemporal_store(bf16r(u1), out + i + 1);
        __builtin_nontemporal_store(bf16r(u2), out + i + 2);
    }
}

extern "C" void kernel_launch(void* const* d_in, const int* in_sizes, int n_in,
                              void* d_out, int out_size, void* d_ws, size_t ws_size,
                              hipStream_t stream) {
    const float* data = (const float*)d_in[0];
    const int* loc    = (const int*)d_in[1];
    float* out        = (float*)d_out;

    // ws layout (16B aligned): mask | ukeys | W | WP | Bsums   ~730 KB
    const size_t offMask  = 0;
    const size_t offKeys  = offMask + (size_t)M * 8;
    const size_t offW     = offKeys + (size_t)M * 4;
    const size_t offWP    = offW + (size_t)NWPAD * 4;
    const size_t offBs    = offWP + (size_t)NWPAD * 4;
    const size_t bytesAll = offBs + (size_t)(NSB + 64) * 4;

    char* basep = (ws_size >= bytesAll) ? (char*)d_ws : (char*)d_out;
    // (fallback: d_out head is dead until k_out, the only later writer)

    unsigned long long* mask = (unsigned long long*)(basep + offMask);
    int*      ukeys = (int*)(basep + offKeys);
    unsigned* W     = (unsigned*)(basep + offW);
    unsigned* WP    = (unsigned*)(basep + offWP);
    int*      Bsums = (int*)(basep + offBs);

    long long out_sz  = (long long)out_size;                // 33,700,800 floats
    long long base_ul = out_sz - (long long)3 * M;          // 33,600,000

    k_zero<<<40, 256, 0, stream>>>((int4*)W);
    k_mark<<<(M + 255) / 256, 256, 0, stream>>>(loc, W, (int4*)mask);
    k_scan_words<<<NSB, 256, 0, stream>>>(W, WP, Bsums);
    k_slots<<<(M + 255) / 256, 256, 0, stream>>>(loc, W, WP, Bsums, ukeys, mask);
    k_out<<<NQ, 256, 0, stream>>>(data, loc, ukeys, mask, out, base_ul);
}

// Round 12
// 59.993 us; speedup vs baseline: 1.0961x; 1.0961x over previous
//
#include <hip/hip_runtime.h>
#include <hip/hip_bf16.h>

namespace {
constexpr int NB    = 64;
constexpr int V0d   = 40, V1d = 40, V2d = 200;
constexpr int VOL   = V0d * V1d * V2d;        // 320,000
constexpr int NC0   = 5, NC1 = 5, NC2 = 21;
constexpr int CELLS = NC0 * NC1 * NC2;        // 525
constexpr int M     = NB * CELLS;             // 33600
constexpr int C1MAX = 104, C2MAX = 120;
constexpr int KS    = 104 * C1MAX * C2MAX;    // 1,297,920 dense compact keys
constexpr int NWORDS = KS / 32;               // 40,560 bitmask words
constexpr int NSB    = (NWORDS + 255) / 256;  // 159 scan blocks
constexpr int NWPAD  = NSB * 256;             // 40,704
constexpr int CHVOL  = 1000;
}

typedef float f32x4 __attribute__((ext_vector_type(4)));

// Round through bf16 (expected outputs are bf16-rounded float32 values).
__device__ __forceinline__ float bf16r(float v) {
    return __bfloat162float(__float2bfloat16(v));
}

__device__ __forceinline__ int enc(int c0, int c1, int c2) {
    return (c0 * C1MAX + c1) * C2MAX + c2;
}

// zero key-bitmask W only (162 KB)
__global__ void k_zero(int4* __restrict__ W4) {
    int idx = blockIdx.x * blockDim.x + threadIdx.x;
    int stride = gridDim.x * blockDim.x;
    const int w4 = NWORDS / 4;          // 10,140
    for (int i = idx; i < w4; i += stride) W4[i] = make_int4(0, 0, 0, 0);
}

// mark keys; also zero the contributor masks (disjoint array, consumed only
// by the later k_slots kernel -> no intra-kernel ordering hazard)
__global__ void k_mark(const int* __restrict__ loc, unsigned* __restrict__ W,
                       int4* __restrict__ mask4) {
    int m = blockIdx.x * blockDim.x + threadIdx.x;
    if (m < M * 8 / 16) mask4[m] = make_int4(0, 0, 0, 0);   // 16,800 int4
    if (m >= M) return;
    int b = m / CELLS, cell = m % CELLS;
    int i = cell / (NC1 * NC2), j = (cell / NC2) % NC1, k = cell % NC2;
    int d = enc(loc[b * 3 + 0] / 10 + i, loc[b * 3 + 1] / 10 + j,
                loc[b * 3 + 2] / 10 + k);
    atomicOr(&W[d >> 5], 1u << (d & 31));
}

// per-word exclusive popcount prefix within each 256-word block
__global__ __launch_bounds__(256) void k_scan_words(const unsigned* __restrict__ W,
                                                    unsigned* __restrict__ WP,
                                                    int* __restrict__ Bsums) {
    int t = threadIdx.x;
    int w = blockIdx.x * 256 + t;
    int c = (w < NWORDS) ? __popc(W[w]) : 0;
    __shared__ int sc[256];
    sc[t] = c;
    __syncthreads();
#pragma unroll
    for (int off = 1; off < 256; off <<= 1) {
        int x = (t >= off) ? sc[t - off] : 0;
        __syncthreads();
        sc[t] += x;
        __syncthreads();
    }
    int incl = sc[t];
    WP[w] = (unsigned)(incl - c);
    if (t == 255) Bsums[blockIdx.x] = incl;
}

// rank every tile; block-local redundant scan of the 159 Bsums replaces a
// separate scan launch. Record unique key + contributor bitmask per rank.
__global__ __launch_bounds__(256) void k_slots(const int* __restrict__ loc,
        const unsigned* __restrict__ W, const unsigned* __restrict__ WP,
        const int* __restrict__ Bsums, int* __restrict__ ukeys,
        unsigned long long* __restrict__ mask) {
    int t = threadIdx.x;
    __shared__ int sBase[256];
    __shared__ int sc[256];
    int bv = (t < NSB) ? Bsums[t] : 0;
    sc[t] = bv;
    __syncthreads();
#pragma unroll
    for (int off = 1; off < 256; off <<= 1) {
        int x = (t >= off) ? sc[t - off] : 0;
        __syncthreads();
        sc[t] += x;
        __syncthreads();
    }
    sBase[t] = sc[t] - bv;               // exclusive prefix of block sums
    __syncthreads();

    int m = blockIdx.x * blockDim.x + t;
    if (m >= M) return;
    int b = m / CELLS, cell = m % CELLS;
    int i = cell / (NC1 * NC2), j = (cell / NC2) % NC1, k = cell % NC2;
    int d = enc(loc[b * 3 + 0] / 10 + i, loc[b * 3 + 1] / 10 + j,
                loc[b * 3 + 2] / 10 + k);
    int w = d >> 5, bp = d & 31;
    int rank = sBase[w >> 8] + (int)WP[w] + __popc(W[w] & ((1u << bp) - 1u));
    ukeys[rank] = d;                     // same value from all writers
    atomicOr(&mask[rank], 1ull << b);    // order-independent -> deterministic
}

// one block per output slot; R10-proven gather structure (empirical optimum
// across 6 tested variants) + non-temporal stores.
__global__ __launch_bounds__(256) void k_out(const float* __restrict__ data,
        const int* __restrict__ loc, const int* __restrict__ ukeys,
        const unsigned long long* __restrict__ mask,
        float* __restrict__ out, long long base_ul) {
    // bijective XCD swizzle: M = 33600 = 8 * 4200
    int orig = blockIdx.x;
    int r = (orig & 7) * (M / 8) + (orig >> 3);
    int t = threadIdx.x;

    unsigned long long mk = mask[r];     // uniform -> s_load
    int key = ukeys[r];                  // uniform -> s_load (garbage if !valid)
    bool valid = (mk != 0ull);

    float ax = 0.f, ay = 0.f, az = 0.f, aw = 0.f;
    int c0 = 0, c1 = 0, c2 = 0;
    if (valid) {
        c0 = key / (C1MAX * C2MAX);
        int rem = key % (C1MAX * C2MAX);
        c1 = rem / C2MAX;
        c2 = rem % C2MAX;
        if (t < 250) {
            int e0 = t * 4;
            int x  = e0 / 100;
            int rm = e0 % 100;
            int y  = rm / 10;
            int z0 = rm % 10;            // in {0,2,4,6,8}
            int g0 = c0 * 10, g1 = c1 * 10, g2 = c2 * 10;
            unsigned long long m2 = mk;
            while (m2) {                 // ascending b == numpy order
                int b = __builtin_ctzll(m2);
                m2 &= m2 - 1;
                int l0 = loc[b * 3 + 0], l1 = loc[b * 3 + 1], l2 = loc[b * 3 + 2];
                const float* db = data + (size_t)b * VOL;
                if (z0 <= 6) {
                    // all 4 elems share one source row (x,y)
                    int p0 = g0 - l0 + x, p1 = g1 - l1 + y, p2 = g2 - l2 + z0;
                    if ((unsigned)p0 < (unsigned)V0d &&
                        (unsigned)p1 < (unsigned)V1d) {
                        const float* s = db + (p0 * V1d + p1) * V2d + p2;
                        if (p2 >= 0 && p2 <= V2d - 4) {
                            ax += s[0]; ay += s[1]; az += s[2]; aw += s[3];
                        } else {
                            if ((unsigned)p2       < (unsigned)V2d) ax += s[0];
                            if ((unsigned)(p2 + 1) < (unsigned)V2d) ay += s[1];
                            if ((unsigned)(p2 + 2) < (unsigned)V2d) az += s[2];
                            if ((unsigned)(p2 + 3) < (unsigned)V2d) aw += s[3];
                        }
                    }
                } else {
                    // z0 == 8: group straddles a y-row boundary; per-element
                    float av[4] = {0.f, 0.f, 0.f, 0.f};
#pragma unroll
                    for (int jj = 0; jj < 4; ++jj) {
                        int e  = e0 + jj;
                        int xx = e / 100;
                        int rj = e % 100;
                        int yy = rj / 10, zz = rj % 10;
                        int q0 = g0 - l0 + xx, q1 = g1 - l1 + yy,
                            q2 = g2 - l2 + zz;
                        if ((unsigned)q0 < (unsigned)V0d &&
                            (unsigned)q1 < (unsigned)V1d &&
                            (unsigned)q2 < (unsigned)V2d)
                            av[jj] = db[(q0 * V1d + q1) * V2d + q2];
                    }
                    ax += av[0]; ay += av[1]; az += av[2]; aw += av[3];
                }
            }
        }
    }

    if (t < 250) {
        f32x4 v = {bf16r(ax), bf16r(ay), bf16r(az), bf16r(aw)};
        __builtin_nontemporal_store(v,
            reinterpret_cast<f32x4*>(out + (long long)r * CHVOL + t * 4));
    }
    if (t == 0) {  // fused uloc write (output 1)
        float u0, u1, u2;
        if (valid) {
            u0 = (float)(c0 * 10);
            u1 = (float)(c1 * 10);
            u2 = (float)(c2 * 10);
        } else {  // jnp.unique fill 2^31-1 decoded: (327670, 2550, 2550)
            u0 = 327670.f; u1 = 2550.f; u2 = 2550.f;
        }
        long long i = base_ul + (long long)r * 3;
        __builtin_nontemporal_store(bf16r(u0), out + i + 0);
        __builtin_nontemporal_store(bf16r(u1), out + i + 1);
        __builtin_nontemporal_store(bf16r(u2), out + i + 2);
    }
}

extern "C" void kernel_launch(void* const* d_in, const int* in_sizes, int n_in,
                              void* d_out, int out_size, void* d_ws, size_t ws_size,
                              hipStream_t stream) {
    const float* data = (const float*)d_in[0];
    const int* loc    = (const int*)d_in[1];
    float* out        = (float*)d_out;

    // ws layout (16B aligned): mask | ukeys | W | WP | Bsums   ~730 KB
    const size_t offMask  = 0;
    const size_t offKeys  = offMask + (size_t)M * 8;
    const size_t offW     = offKeys + (size_t)M * 4;
    const size_t offWP    = offW + (size_t)NWPAD * 4;
    const size_t offBs    = offWP + (size_t)NWPAD * 4;
    const size_t bytesAll = offBs + (size_t)(NSB + 64) * 4;

    char* basep = (ws_size >= bytesAll) ? (char*)d_ws : (char*)d_out;
    // (fallback: d_out head is dead until k_out, the only later writer)

    unsigned long long* mask = (unsigned long long*)(basep + offMask);
    int*      ukeys = (int*)(basep + offKeys);
    unsigned* W     = (unsigned*)(basep + offW);
    unsigned* WP    = (unsigned*)(basep + offWP);
    int*      Bsums = (int*)(basep + offBs);

    long long out_sz  = (long long)out_size;                // 33,700,800 floats
    long long base_ul = out_sz - (long long)3 * M;          // 33,600,000

    k_zero<<<40, 256, 0, stream>>>((int4*)W);
    k_mark<<<(M + 255) / 256, 256, 0, stream>>>(loc, W, (int4*)mask);
    k_scan_words<<<NSB, 256, 0, stream>>>(W, WP, Bsums);
    k_slots<<<(M + 255) / 256, 256, 0, stream>>>(loc, W, WP, Bsums, ukeys, mask);
    k_out<<<M, 256, 0, stream>>>(data, loc, ukeys, mask, out, base_ul);
}